// Round 7
// baseline (351.979 us; speedup 1.0000x reference)
//
#include <hip/hip_runtime.h>
#include <hip/hip_cooperative_groups.h>
#include <cstdint>

#define BB 64
#define PP 8732
#define CC 81
#define QR 2183            // priors per block = PP/4
#define TILE 128           // priors per softmax tile
#define NT 18              // 17 full tiles + 1 tail tile
#define TAIL 7             // QR - 17*TILE
#define NBLK 256           // 1 block per CU (cooperative, co-resident)
#define NTHR 1024

#define GLOBAL_AS __attribute__((address_space(1)))
#define LDS_AS __attribute__((address_space(3)))

namespace cg = cooperative_groups;

__device__ __forceinline__ float wsum(float v) {
#pragma unroll
  for (int o = 32; o > 0; o >>= 1) v += __shfl_xor(v, o, 64);
  return v;
}
__device__ __forceinline__ int wsumi(int v) {
#pragma unroll
  for (int o = 32; o > 0; o >>= 1) v += __shfl_xor(v, o, 64);
  return v;
}

// async DMA of nf floats, 16B chunks + 4B tail
__device__ __forceinline__ void dma_floats(const float* gsrc, float* ldst,
                                           int nf, int tid) {
  const GLOBAL_AS float* g = (const GLOBAL_AS float*)gsrc;
  LDS_AS float* l = (LDS_AS float*)ldst;
  const int n4 = nf >> 2;
  for (int i = tid; i < n4; i += NTHR)
    __builtin_amdgcn_global_load_lds((const GLOBAL_AS void*)(g + 4 * i),
                                     (LDS_AS void*)(l + 4 * i), 16, 0, 0);
  const int rem = nf & 3;
  if (tid < rem)
    __builtin_amdgcn_global_load_lds((const GLOBAL_AS void*)(g + 4 * n4 + tid),
                                     (LDS_AS void*)(l + 4 * n4 + tid), 4, 0, 0);
}

#define RREP 16
#define HSTR 257

// One fused cooperative kernel: phase 1 (rowstats, 256 blocks, streamed
// double-buffered DMA pipeline) -> grid.sync -> phase 2 (top-K radix select,
// blocks 0..63) -> grid.sync -> phase 3 (final, block 0).
__global__ __launch_bounds__(NTHR, 1) void k_fused(
    const float* __restrict__ conf, const float* __restrict__ ploc,
    const int* __restrict__ label, const float* __restrict__ gloc,
    float* __restrict__ negp, int* __restrict__ part_cnt,
    float* __restrict__ part_nll, float* __restrict__ part_loc,
    int* __restrict__ row_npos, float* __restrict__ row_nll,
    float* __restrict__ row_loc, float* __restrict__ row_topk,
    float* __restrict__ out) {
  // 82944 B overlay: phase 1 = two 41472 B tile buffers; phase 2 = s_v(34928)
  // + hist(16448) + tot(1024)
  __shared__ __align__(16) unsigned char s_mem[2 * TILE * CC * 4];
  __shared__ float sh_n[NTHR / 64], sh_l[NTHR / 64], sh_f[NTHR / 64];
  __shared__ int sh_c[NTHR / 64];
  __shared__ uint32_t s_pref;
  __shared__ int s_kk, s_npos;

  cg::grid_group grid = cg::this_grid();

  const int g = blockIdx.x;
  const int b = g >> 2, qy = g & 3;
  const int tid = threadIdx.x;
  const int lane = tid & 63, wave = tid >> 6;

  float* buf0 = (float*)s_mem;
  float* buf1 = buf0 + TILE * CC;
  const size_t rowbase = (size_t)b * PP + (size_t)qy * QR;
  const float* cbase = conf + rowbase * CC;

  // ================= phase 1: rowstats over this block's quarter-row ======
  // kick tile 0 DMA, then do the loc/cnt pre-sweep while it flies
  dma_floats(cbase, buf0, TILE * CC, tid);

  float loc_acc = 0.0f, nll_acc = 0.0f;
  int cnt = 0;
  for (int i = tid; i < QR * 4; i += NTHR) {
    const int p = i >> 2;
    const int lab = label[rowbase + p];   // 4 adjacent lanes same addr
    if (lab > 0) {                        // skips ~97% of ploc/gloc traffic
      const size_t idx = rowbase * 4 + i;
      const float df = ploc[idx] - gloc[idx];
      const float ad = fabsf(df);
      loc_acc += (ad < 1.0f) ? 0.5f * df * df : ad - 0.5f;
      if ((i & 3) == 0) cnt++;
    }
  }

  // streamed tile loop: barrier drains tile t, issue t+1, compute t
  const int p_l = tid >> 3, q = tid & 7;  // 8 threads per prior
  for (int t = 0; t < NT; ++t) {
    __syncthreads();                      // drains tile t's DMA (t+1 not yet issued)
    if (t + 1 < NT) {
      const int nf = (t + 1 == NT - 1) ? TAIL * CC : TILE * CC;
      dma_floats(cbase + (size_t)(t + 1) * TILE * CC,
                 ((t + 1) & 1) ? buf1 : buf0, nf, tid);
    }
    const int np = (t == NT - 1) ? TAIL : TILE;
    if (p_l < np) {                       // compute tile t overlaps t+1 flight
      const float* xr = ((t & 1) ? buf1 : buf0) + p_l * CC;
      float s = 0.0f;
      for (int c = q; c < CC; c += 8) s += __expf(xr[c]);
      s += __shfl_xor(s, 1, 64);
      s += __shfl_xor(s, 2, 64);
      s += __shfl_xor(s, 4, 64);
      if (q == 0) {
        const float lse = __logf(s);
        const int gp = t * TILE + p_l;
        const int lab = label[rowbase + gp];
        const bool pos = lab > 0;
        negp[rowbase + gp] = pos ? 0.0f : fmaxf(lse - xr[0], 0.0f);
        if (pos) nll_acc += lse - xr[lab];
      }
    }
  }

  // block reduce -> one partial slot per block
  {
    const float na = wsum(nll_acc);
    const float la = wsum(loc_acc);
    const int ca = wsumi(cnt);
    if (lane == 0) { sh_n[wave] = na; sh_l[wave] = la; sh_c[wave] = ca; }
    __syncthreads();
    if (tid == 0) {
      float tn = 0.0f, tl = 0.0f; int tc = 0;
#pragma unroll
      for (int w = 0; w < NTHR / 64; ++w) { tn += sh_n[w]; tl += sh_l[w]; tc += sh_c[w]; }
      part_cnt[g] = tc; part_nll[g] = tn; part_loc[g] = tl;
    }
  }

  grid.sync();   // ============ all negp + partials visible device-wide =====

  // ================= phase 2: top-K radix select, one block per row =======
  if (g < BB) {
    uint32_t* s_v = (uint32_t*)s_mem;             // 34928 B
    int* s_hist = (int*)(s_mem + 34928);          // 16448 B
    int* s_tot = (int*)(s_mem + 34928 + 16448);   // 1024 B

    dma_floats(negp + (size_t)g * PP, (float*)s_v, PP, tid);

    if (tid == 0) {
      const int i4 = g * 4;
      const int tc = part_cnt[i4] + part_cnt[i4 + 1] + part_cnt[i4 + 2] + part_cnt[i4 + 3];
      const float tn = part_nll[i4] + part_nll[i4 + 1] + part_nll[i4 + 2] + part_nll[i4 + 3];
      const float tl = part_loc[i4] + part_loc[i4 + 1] + part_loc[i4 + 2] + part_loc[i4 + 3];
      row_npos[g] = tc; row_nll[g] = tn; row_loc[g] = tl;
      s_npos = tc; s_pref = 0u;
    }
    for (int i = tid; i < RREP * HSTR; i += NTHR) s_hist[i] = 0;
    __syncthreads();                      // drains DMA, publishes s_npos

    const int npos = s_npos;
    int K = 3 * npos;
    const int mx = PP - npos;
    if (K > mx) K = mx;

    if (K > 0) {                          // block-uniform
      if (tid == 0) s_kk = K;
      __syncthreads();
      const int rep = tid & (RREP - 1);

      for (int pass = 0; pass < 4; ++pass) {
        const int sh = 24 - 8 * pass;
        const uint32_t himask = (pass == 0) ? 0u : (0xFFFFFFFFu << (sh + 8));
        const uint32_t pref = s_pref;
        for (int i = tid; i < PP; i += NTHR) {
          const uint32_t u = s_v[i];
          if ((u & himask) == (pref & himask))
            atomicAdd(&s_hist[rep * HSTR + ((u >> sh) & 0xFF)], 1);
        }
        __syncthreads();
        if (tid < 256) {
          int tt = 0;
#pragma unroll
          for (int r = 0; r < RREP; ++r) tt += s_hist[r * HSTR + tid];
          s_tot[tid] = tt;
        }
        __syncthreads();
        for (int i = tid; i < RREP * HSTR; i += NTHR) s_hist[i] = 0;
        if (tid < 64) {                   // wave-0 suffix-scan threshold pick
          const int l = tid;
          const int e0 = s_tot[4 * l], e1 = s_tot[4 * l + 1];
          const int e2 = s_tot[4 * l + 2], e3 = s_tot[4 * l + 3];
          const int L = e0 + e1 + e2 + e3;
          int x = L;
#pragma unroll
          for (int o = 1; o < 64; o <<= 1) {
            const int v = __shfl_down(x, o, 64);
            if (l + o < 64) x += v;
          }
          const int T = x - L;
          const int S3 = e3 + T, S2 = e2 + S3, S1 = e1 + S2, S0 = e0 + S1;
          const int kk = s_kk;
          const uint32_t pf = s_pref;
          if (S0 >= kk && S1 < kk) { s_pref = pf | ((uint32_t)(4 * l + 0) << sh); s_kk = kk - S1; }
          if (S1 >= kk && S2 < kk) { s_pref = pf | ((uint32_t)(4 * l + 1) << sh); s_kk = kk - S2; }
          if (S2 >= kk && S3 < kk) { s_pref = pf | ((uint32_t)(4 * l + 2) << sh); s_kk = kk - S3; }
          if (S3 >= kk && T  < kk) { s_pref = pf | ((uint32_t)(4 * l + 3) << sh); s_kk = kk - T; }
        }
        __syncthreads();
      }

      const uint32_t T = s_pref;
      const int kk = s_kk;
      float local = 0.0f;
      for (int i = tid; i < PP; i += NTHR) {
        const uint32_t u = s_v[i];
        if (u > T) local += __uint_as_float(u);
      }
      local = wsum(local);
      if (lane == 0) sh_f[wave] = local;
      __syncthreads();
      if (tid == 0) {
        float tot = 0.0f;
#pragma unroll
        for (int w = 0; w < NTHR / 64; ++w) tot += sh_f[w];
        row_topk[g] = tot + (float)kk * __uint_as_float(T);
      }
    } else {
      if (tid == 0) row_topk[g] = 0.0f;
    }
  }

  grid.sync();   // ============ row_* arrays visible ========================

  // ================= phase 3: finalize (block 0, one wave) ================
  if (g == 0 && tid < 64) {
    const int npos = row_npos[tid];
    const float nll = row_nll[tid] + row_topk[tid];
    const float loc = row_loc[tid];
    int K = 3 * npos;
    const int mx = PP - npos;
    if (K > mx) K = mx;
    const float nsel = (float)(npos + K);

    const float tot_nll = wsum(nll);
    const float tot_loc = wsum(loc);
    const float tot_pos = wsum((float)npos);
    const float tot_sel = wsum(nsel);

    const float ce = tot_nll / fmaxf(tot_sel, 1.0f);
    out[tid] = ce / (float)npos;                       // conf_loss (B,1)
    if (tid == 0) out[BB] = tot_loc / fmaxf(tot_pos, 1.0f);  // loc_huber_loss
  }
}

extern "C" void kernel_launch(void* const* d_in, const int* in_sizes, int n_in,
                              void* d_out, int out_size, void* d_ws, size_t ws_size,
                              hipStream_t stream) {
  const float* conf = (const float*)d_in[0];
  const float* ploc = (const float*)d_in[1];
  const int* label = (const int*)d_in[2];
  const float* gloc = (const float*)d_in[3];
  float* out = (float*)d_out;

  float* negp = (float*)d_ws;                          // BB*PP floats
  int* part_cnt = (int*)(negp + (size_t)BB * PP);      // NBLK ints
  float* part_nll = (float*)(part_cnt + NBLK);         // NBLK floats
  float* part_loc = part_nll + NBLK;                   // NBLK floats
  int* row_npos = (int*)(part_loc + NBLK);             // BB ints
  float* row_nll = (float*)(row_npos + BB);            // BB floats
  float* row_loc = row_nll + BB;                       // BB floats
  float* row_topk = row_loc + BB;                      // BB floats

  void* args[] = {
      (void*)&conf, (void*)&ploc, (void*)&label, (void*)&gloc,
      (void*)&negp, (void*)&part_cnt, (void*)&part_nll, (void*)&part_loc,
      (void*)&row_npos, (void*)&row_nll, (void*)&row_loc, (void*)&row_topk,
      (void*)&out};
  hipLaunchCooperativeKernel((void*)k_fused, dim3(NBLK), dim3(NTHR),
                             args, 0, stream);
}